// Round 2
// baseline (79.890 us; speedup 1.0000x reference)
//
#include <hip/hip_runtime.h>
#include <math.h>

// BlockMaskGenerator: 4 random rectangles per batch -> target mask (OR of rects),
// context mask = complement. Output dtype is INT32 (reference returns bool;
// harness reads d_out as int32 -> round-1 absmax 1065353215 == bits(1.0f)-1
// proved float stores were wrong). Layout: [context(256x16384), target(256x16384)].
//
// Geometry math must EXACTLY match numpy f32 semantics:
//   scales = 0.15 + u*0.05                      (f32 ops, correctly rounded)
//   area   = trunc_i32(scales * 128 * 128)      (x128 is exact exponent shift)
//   bh     = clip(trunc_i32(sqrt_f32(area_f / 0.75)), 1, 128)
//   bw     = clip(trunc_i32(area_f / bh), 1, 128)
//   top    = trunc_i32(rand_top * (129 - bh)); left likewise
// sqrt/div computed in double then rounded to f32: provably equal to correctly-
// rounded f32 ops for these operand ranges, and immune to fast-math approx
// (area*4/3 can be an exact perfect square -> a 1-ulp-low v_sqrt_f32 would
// flip the truncation and corrupt the mask).

constexpr int H = 128, W = 128, NB = 4, BATCH = 256;
constexpr int SEQ = H * W;
constexpr int ROWS_PER_WG = 32;                 // gridDim.y = 4 row-groups
constexpr int V4_PER_WG = ROWS_PER_WG * W / 4;  // 1024 int4 per output per WG

__global__ __launch_bounds__(256) void blockmask_kernel(
    const float* __restrict__ scales_u,
    const float* __restrict__ rand_top,
    const float* __restrict__ rand_left,
    int* __restrict__ out)
{
    const int b  = blockIdx.x;   // batch
    const int rg = blockIdx.y;   // row group (32 rows each)

    int tops[NB], bots[NB], lefts[NB], rights[NB];
#pragma unroll
    for (int j = 0; j < NB; ++j) {
        const int idx = b * NB + j;
        const float s = 0.15f + scales_u[idx] * 0.05f;
        const int area = (int)(s * 16384.0f);            // exact shift, then trunc
        const float areaf = (float)area;
        // f32-correctly-rounded divide + sqrt via double (see header comment)
        const float x = (float)((double)areaf / 0.75);
        int bh = (int)((float)sqrt((double)x));
        bh = bh < 1 ? 1 : (bh > H ? H : bh);
        int bw = (int)((float)((double)areaf / (double)bh));
        bw = bw < 1 ? 1 : (bw > W ? W : bw);
        int maxt = H - bh + 1; if (maxt < 1) maxt = 1;
        int maxl = W - bw + 1; if (maxl < 1) maxl = 1;
        const int top  = (int)(rand_top[idx]  * (float)maxt);
        const int left = (int)(rand_left[idx] * (float)maxl);
        tops[j]  = top;  bots[j]   = top + bh;
        lefts[j] = left; rights[j] = left + bw;
    }

    const size_t batchBase = (size_t)b * SEQ;            // elements
    int4* __restrict__ ctx =
        reinterpret_cast<int4*>(out) + (batchBase >> 2);
    int4* __restrict__ tgt =
        reinterpret_cast<int4*>(out + (size_t)BATCH * SEQ) + (batchBase >> 2);

    const int regionBase = rg * V4_PER_WG;               // int4 index in batch
    for (int i = threadIdx.x; i < V4_PER_WG; i += 256) {
        const int v4  = regionBase + i;
        const int pos = v4 * 4;
        const int r   = pos >> 7;        // W == 128
        const int c0  = pos & (W - 1);
        int v[4];
#pragma unroll
        for (int k = 0; k < 4; ++k) {
            const int c = c0 + k;
            bool in = false;
#pragma unroll
            for (int j = 0; j < NB; ++j)
                in = in || (r >= tops[j] && r < bots[j] &&
                            c >= lefts[j] && c < rights[j]);
            v[k] = in ? 1 : 0;
        }
        tgt[v4] = make_int4(v[0], v[1], v[2], v[3]);
        ctx[v4] = make_int4(1 - v[0], 1 - v[1], 1 - v[2], 1 - v[3]);
    }
}

extern "C" void kernel_launch(void* const* d_in, const int* in_sizes, int n_in,
                              void* d_out, int out_size, void* d_ws, size_t ws_size,
                              hipStream_t stream) {
    const float* scales_u = (const float*)d_in[0];
    const float* rand_top = (const float*)d_in[1];
    const float* rand_left = (const float*)d_in[2];
    int* out = (int*)d_out;
    blockmask_kernel<<<dim3(BATCH, 4), 256, 0, stream>>>(
        scales_u, rand_top, rand_left, out);
}

// Round 3
// 79.226 us; speedup vs baseline: 1.0084x; 1.0084x over previous
//
#include <hip/hip_runtime.h>
#include <math.h>

// BlockMaskGenerator: 4 random rectangles per batch -> target mask (OR of rects),
// context mask = complement. Output dtype INT32 (harness reads bool refs as i32).
// Layout: [context(256x16384), target(256x16384)].
//
// R2 post-mortem: passed @79.9us, but top-5 dispatches are all harness
// fillBuffer (256MiB d_ws poison @42us, 79% peak) -> our kernel <42us.
// Split: kernel1 computes 1024 rect bounds (f64 sqrt/div for exact numpy-f32
// rounding) into d_ws once; kernel2 is a pure store machine with rects in
// SGPRs (wave-uniform s_load) and 4x16B coalesced stores per thread.
//
// Geometry must EXACTLY match numpy f32 semantics:
//   scales = 0.15 + u*0.05 ; area = trunc(scales*16384) (x16384 exact)
//   bh = clip(trunc(sqrt_f32(area/0.75)),1,128); bw = clip(trunc(area/bh),1,128)
//   top = trunc(rand_top*(129-bh)); left likewise.
// sqrt/div via double then round to f32 == correctly-rounded f32 ops for these
// ranges; immune to fast-math v_sqrt_f32 approx (area*4/3 can be a perfect
// square -> 1-ulp-low sqrt would flip truncation).

constexpr int H = 128, W = 128, NB = 4, BATCH = 256;
constexpr int SEQ = H * W;
constexpr int TOTAL = BATCH * NB;  // 1024 rects

__global__ __launch_bounds__(256) void rect_kernel(
    const float* __restrict__ scales_u,
    const float* __restrict__ rand_top,
    const float* __restrict__ rand_left,
    int4* __restrict__ rects)
{
    const int idx = blockIdx.x * 256 + threadIdx.x;   // 0..1023
    const float s = 0.15f + scales_u[idx] * 0.05f;
    const int area = (int)(s * 16384.0f);             // exact shift, then trunc
    const float areaf = (float)area;
    const float x = (float)((double)areaf / 0.75);    // f32-correctly-rounded
    int bh = (int)((float)sqrt((double)x));
    bh = bh < 1 ? 1 : (bh > H ? H : bh);
    int bw = (int)((float)((double)areaf / (double)bh));
    bw = bw < 1 ? 1 : (bw > W ? W : bw);
    int maxt = H - bh + 1; if (maxt < 1) maxt = 1;
    int maxl = W - bw + 1; if (maxl < 1) maxl = 1;
    const int top  = (int)(rand_top[idx]  * (float)maxt);
    const int left = (int)(rand_left[idx] * (float)maxl);
    rects[idx] = make_int4(top, top + bh, left, left + bw);
}

// Grid: 2048 WGs = 256 batches x 8 segments (16 rows each).
// Thread: rr = tid>>5 (0..7), col0 = (tid&31)*4. Writes rows seg*16+rr and
// seg*16+rr+8 for both outputs -> 4 x global_store_dwordx4, each instruction
// fully contiguous across the wave (1 KiB/instr).
__global__ __launch_bounds__(256) void mask_kernel(
    const int4* __restrict__ rects,
    int* __restrict__ out)
{
    const int b   = blockIdx.x >> 3;
    const int seg = blockIdx.x & 7;

    // Wave-uniform address -> scalar loads; rects land in SGPRs.
    const int4 R0 = rects[b * NB + 0];
    const int4 R1 = rects[b * NB + 1];
    const int4 R2 = rects[b * NB + 2];
    const int4 R3 = rects[b * NB + 3];

    const int tid  = threadIdx.x;
    const int rowA = seg * 16 + (tid >> 5);
    const int rowB = rowA + 8;
    const int col0 = (tid & 31) * 4;

    int4* const ctx = reinterpret_cast<int4*>(out);
    int4* const tgt = reinterpret_cast<int4*>(out + (size_t)BATCH * SEQ);
    const int baseA = (b * SEQ + rowA * W + col0) >> 2;   // int4 index
    const int baseB = (b * SEQ + rowB * W + col0) >> 2;

    int vA[4], vB[4];
#pragma unroll
    for (int k = 0; k < 4; ++k) {
        const int c = col0 + k;
        const bool c0 = (c >= R0.z) & (c < R0.w);
        const bool c1 = (c >= R1.z) & (c < R1.w);
        const bool c2 = (c >= R2.z) & (c < R2.w);
        const bool c3 = (c >= R3.z) & (c < R3.w);
        const bool inA = (c0 & (rowA >= R0.x) & (rowA < R0.y)) |
                         (c1 & (rowA >= R1.x) & (rowA < R1.y)) |
                         (c2 & (rowA >= R2.x) & (rowA < R2.y)) |
                         (c3 & (rowA >= R3.x) & (rowA < R3.y));
        const bool inB = (c0 & (rowB >= R0.x) & (rowB < R0.y)) |
                         (c1 & (rowB >= R1.x) & (rowB < R1.y)) |
                         (c2 & (rowB >= R2.x) & (rowB < R2.y)) |
                         (c3 & (rowB >= R3.x) & (rowB < R3.y));
        vA[k] = inA ? 1 : 0;
        vB[k] = inB ? 1 : 0;
    }
    tgt[baseA] = make_int4(vA[0], vA[1], vA[2], vA[3]);
    tgt[baseB] = make_int4(vB[0], vB[1], vB[2], vB[3]);
    ctx[baseA] = make_int4(1 - vA[0], 1 - vA[1], 1 - vA[2], 1 - vA[3]);
    ctx[baseB] = make_int4(1 - vB[0], 1 - vB[1], 1 - vB[2], 1 - vB[3]);
}

extern "C" void kernel_launch(void* const* d_in, const int* in_sizes, int n_in,
                              void* d_out, int out_size, void* d_ws, size_t ws_size,
                              hipStream_t stream) {
    const float* scales_u  = (const float*)d_in[0];
    const float* rand_top  = (const float*)d_in[1];
    const float* rand_left = (const float*)d_in[2];
    int4* rects = (int4*)d_ws;          // 1024 * 16 B = 16 KB scratch
    int* out = (int*)d_out;

    rect_kernel<<<TOTAL / 256, 256, 0, stream>>>(scales_u, rand_top, rand_left, rects);
    mask_kernel<<<BATCH * 8, 256, 0, stream>>>(rects, out);
}

// Round 4
// 75.927 us; speedup vs baseline: 1.0522x; 1.0435x over previous
//
#include <hip/hip_runtime.h>
#include <math.h>

// BlockMaskGenerator: 4 random rectangles per batch -> target mask (OR of rects),
// context mask = complement. Output dtype INT32 (harness reads bool refs as i32).
// Layout: [context(256x16384), target(256x16384)].
//
// R3 post-mortem: 79.2us total, dominated by fixed harness work (256MiB d_ws
// poison = 42us @79% peak, out poison ~5.3us). Controllable slice ~8us:
// mask kernel (~6us, store floor 5.3us) + rect kernel dispatch (~2us launch/
// dependency gap). R4: fuse — each wave computes its batch's 4 rects (lane&3),
// packs fields into 1 int (all <=128, 8 bits each), broadcasts via 4 __shfl.
//
// Geometry must EXACTLY match numpy f32 semantics:
//   scales = 0.15 + u*0.05 ; area = trunc(scales*16384) (x16384 exact)
//   bh = clip(trunc(sqrt_f32(area/0.75)),1,128); bw = clip(trunc(area/bh),1,128)
//   top = trunc(rand_top*(129-bh)); left likewise.
// sqrt/div via double then round to f32 == correctly-rounded f32 ops for these
// ranges; immune to fast-math v_sqrt_f32 approx (area*4/3 can be a perfect
// square -> 1-ulp-low sqrt would flip truncation).

constexpr int H = 128, W = 128, NB = 4, BATCH = 256;
constexpr int SEQ = H * W;

// Grid: 2048 WGs = 256 batches x 8 segments (16 rows each), 256 threads.
// Thread: rr = tid>>5 (0..7), col0 = (tid&31)*4. Writes rows seg*16+rr and
// seg*16+rr+8 for both outputs -> 4 x global_store_dwordx4, each instruction
// fully contiguous across the wave (1 KiB/instr).
__global__ __launch_bounds__(256) void mask_kernel(
    const float* __restrict__ scales_u,
    const float* __restrict__ rand_top,
    const float* __restrict__ rand_left,
    int* __restrict__ out)
{
    const int b   = blockIdx.x >> 3;
    const int seg = blockIdx.x & 7;
    const int tid = threadIdx.x;
    const int lane = tid & 63;

    // --- per-wave rect computation: every lane computes rect (lane&3) ---
    const int j   = lane & 3;
    const int idx = b * NB + j;
    const float s = 0.15f + scales_u[idx] * 0.05f;
    const int area = (int)(s * 16384.0f);             // exact shift, then trunc
    const float areaf = (float)area;
    const float x = (float)((double)areaf / 0.75);    // f32-correctly-rounded
    int bh = (int)((float)sqrt((double)x));
    bh = bh < 1 ? 1 : (bh > H ? H : bh);
    int bw = (int)((float)((double)areaf / (double)bh));
    bw = bw < 1 ? 1 : (bw > W ? W : bw);
    int maxt = H - bh + 1; if (maxt < 1) maxt = 1;
    int maxl = W - bw + 1; if (maxl < 1) maxl = 1;
    const int top  = (int)(rand_top[idx]  * (float)maxt);
    const int left = (int)(rand_left[idx] * (float)maxl);
    // pack: top|bot|left|right, each 8 bits (max value 128)
    const int packed = (top << 24) | ((top + bh) << 16) | (left << 8) | (left + bw);

    // broadcast the 4 rects across the wave (4 x ds_bpermute)
    const int p0 = __shfl(packed, 0);
    const int p1 = __shfl(packed, 1);
    const int p2 = __shfl(packed, 2);
    const int p3 = __shfl(packed, 3);
    const int t0 = p0 >> 24, b0 = (p0 >> 16) & 255, l0 = (p0 >> 8) & 255, r0 = p0 & 255;
    const int t1 = p1 >> 24, b1 = (p1 >> 16) & 255, l1 = (p1 >> 8) & 255, r1 = p1 & 255;
    const int t2 = p2 >> 24, b2 = (p2 >> 16) & 255, l2 = (p2 >> 8) & 255, r2 = p2 & 255;
    const int t3 = p3 >> 24, b3 = (p3 >> 16) & 255, l3 = (p3 >> 8) & 255, r3 = p3 & 255;

    // --- store machine (identical to R3's verified layout) ---
    const int rowA = seg * 16 + (tid >> 5);
    const int rowB = rowA + 8;
    const int col0 = (tid & 31) * 4;

    int4* const ctx = reinterpret_cast<int4*>(out);
    int4* const tgt = reinterpret_cast<int4*>(out + (size_t)BATCH * SEQ);
    const int baseA = (b * SEQ + rowA * W + col0) >> 2;   // int4 index
    const int baseB = (b * SEQ + rowB * W + col0) >> 2;

    const bool rA0 = (rowA >= t0) & (rowA < b0), rB0 = (rowB >= t0) & (rowB < b0);
    const bool rA1 = (rowA >= t1) & (rowA < b1), rB1 = (rowB >= t1) & (rowB < b1);
    const bool rA2 = (rowA >= t2) & (rowA < b2), rB2 = (rowB >= t2) & (rowB < b2);
    const bool rA3 = (rowA >= t3) & (rowA < b3), rB3 = (rowB >= t3) & (rowB < b3);

    int vA[4], vB[4];
#pragma unroll
    for (int k = 0; k < 4; ++k) {
        const int c = col0 + k;
        const bool c0 = (c >= l0) & (c < r0);
        const bool c1 = (c >= l1) & (c < r1);
        const bool c2 = (c >= l2) & (c < r2);
        const bool c3 = (c >= l3) & (c < r3);
        vA[k] = ((c0 & rA0) | (c1 & rA1) | (c2 & rA2) | (c3 & rA3)) ? 1 : 0;
        vB[k] = ((c0 & rB0) | (c1 & rB1) | (c2 & rB2) | (c3 & rB3)) ? 1 : 0;
    }
    tgt[baseA] = make_int4(vA[0], vA[1], vA[2], vA[3]);
    tgt[baseB] = make_int4(vB[0], vB[1], vB[2], vB[3]);
    ctx[baseA] = make_int4(1 - vA[0], 1 - vA[1], 1 - vA[2], 1 - vA[3]);
    ctx[baseB] = make_int4(1 - vB[0], 1 - vB[1], 1 - vB[2], 1 - vB[3]);
}

extern "C" void kernel_launch(void* const* d_in, const int* in_sizes, int n_in,
                              void* d_out, int out_size, void* d_ws, size_t ws_size,
                              hipStream_t stream) {
    const float* scales_u  = (const float*)d_in[0];
    const float* rand_top  = (const float*)d_in[1];
    const float* rand_left = (const float*)d_in[2];
    int* out = (int*)d_out;
    mask_kernel<<<BATCH * 8, 256, 0, stream>>>(scales_u, rand_top, rand_left, out);
}